// Round 4
// baseline (73.525 us; speedup 1.0000x reference)
//
#include <hip/hip_runtime.h>

// LaughingHyenaModalFilter: out[d,0]=h0[d]; out[d,l]=Re(sum_k R[k,d]*p[k,d]^(l-1)),
// p = r e^{i theta}. K=32, D=1024, L=2048.
//
// One block (128 threads = 2 waves) per d. Thread j owns l in {j, j+128, ...}
// (16 coalesced strided stores). Complex recurrence z_k *= q_k, q_k = p_k^128.
// NO LDS: each wave computes the 32 poles' params in lanes 0..31, then pulls
// them per-pole with v_readlane (full-rate, per-SIMD) instead of 192 ds_read_b32
// broadcasts per wave on the shared per-CU LDS pipe. Init transcendentals use
// native v_exp/v_sin/v_cos (REVOLUTIONS -> theta pre-scaled by 1/2pi + fract).
// Main loop packed as float2 -> v_pk_fma_f32/v_pk_mul_f32 (dual-FP32 rate).

#define KP 32
#define KP2 16
#define DD 1024
#define LL 2048
#define TPB 128
#define NS (LL / TPB)  // 16 steps per thread
#define INV_2PI 0x1.45f306p-3f  // 1/(2*pi)

typedef float v2f __attribute__((ext_vector_type(2)));

__device__ __forceinline__ float rdlane(float x, int k) {
  return __int_as_float(__builtin_amdgcn_readlane(__float_as_int(x), k));
}

__global__ __launch_bounds__(TPB) void modal_filter_kernel(
    const float* __restrict__ r, const float* __restrict__ theta,
    const float* __restrict__ Rre, const float* __restrict__ Rim,
    const float* __restrict__ h0, float* __restrict__ out) {
  const int d = blockIdx.x;
  const int tid = threadIdx.x;
  const int lane = tid & 63;

  // Lane j (mod 32) computes derived params for pole j. Lanes 32..63 duplicate
  // lanes 0..31 (harmless); readlane(k<32) only consumes lanes 0..31.
  const int j = lane & (KP - 1);
  const float rv   = r[j * DD + d];
  const float th   = theta[j * DD + d];
  const float Rrev = Rre[j * DD + d];
  const float Rimv = Rim[j * DD + d];
  const float lr  = __builtin_amdgcn_logf(rv);    // log2(r)
  const float thr = th * INV_2PI;                 // revolutions
  const float qmag = __builtin_amdgcn_exp2f((float)TPB * lr);        // r^128
  const float qang = __builtin_amdgcn_fractf((float)TPB * thr);
  const float qreL = qmag * __builtin_amdgcn_cosf(qang);
  const float qimL = qmag * __builtin_amdgcn_sinf(qang);

  // Init z_k = R_k * p_k^{t0}, t0 = tid-1 (tid 0: t0=-1, p^-1 benign, l=0 slot
  // is overwritten with h0; its later steps t=-1+128s match l-1 exactly).
  v2f ZRE[KP2], ZIM[KP2], QRE[KP2], QIM[KP2];
  const float t0 = (float)tid - 1.0f;
#pragma unroll
  for (int k = 0; k < KP; ++k) {
    const float plr  = rdlane(lr, k);
    const float pthr = rdlane(thr, k);
    const float pRre = rdlane(Rrev, k);
    const float pRim = rdlane(Rimv, k);
    const float mag = __builtin_amdgcn_exp2f(t0 * plr);   // r^t0
    const float ang = __builtin_amdgcn_fractf(t0 * pthr);
    const float c = __builtin_amdgcn_cosf(ang);           // cos(2*pi*ang)
    const float s = __builtin_amdgcn_sinf(ang);
    const float wre = mag * c, wim = mag * s;             // p^t0
    ZRE[k >> 1][k & 1] = pRre * wre - pRim * wim;
    ZIM[k >> 1][k & 1] = pRre * wim + pRim * wre;
    QRE[k >> 1][k & 1] = rdlane(qreL, k);
    QIM[k >> 1][k & 1] = rdlane(qimL, k);
  }

  float* outd = out + (size_t)d * LL;
  const float h0d = h0[d];

#pragma unroll
  for (int s = 0; s < NS; ++s) {
    // h contribution = sum_k Re(z_k); 4 packed accumulators shorten dep chains.
    v2f a0 = {0.f, 0.f}, a1 = {0.f, 0.f}, a2 = {0.f, 0.f}, a3 = {0.f, 0.f};
#pragma unroll
    for (int kk = 0; kk < KP2; kk += 4) {
      a0 += ZRE[kk];
      a1 += ZRE[kk + 1];
      a2 += ZRE[kk + 2];
      a3 += ZRE[kk + 3];
    }
    const v2f aa = (a0 + a1) + (a2 + a3);
    const float acc = aa[0] + aa[1];
    const int l = tid + TPB * s;
    outd[l] = (l == 0) ? h0d : acc;  // wave stores 64 consecutive floats
    if (s < NS - 1) {
#pragma unroll
      for (int kk = 0; kk < KP2; ++kk) {
        const v2f nr = ZRE[kk] * QRE[kk] - ZIM[kk] * QIM[kk];  // v_pk_mul + v_pk_fma
        const v2f ni = ZRE[kk] * QIM[kk] + ZIM[kk] * QRE[kk];
        ZRE[kk] = nr;
        ZIM[kk] = ni;
      }
    }
  }
}

extern "C" void kernel_launch(void* const* d_in, const int* in_sizes, int n_in,
                              void* d_out, int out_size, void* d_ws, size_t ws_size,
                              hipStream_t stream) {
  const float* r     = (const float*)d_in[0];
  const float* theta = (const float*)d_in[1];
  const float* Rre   = (const float*)d_in[2];
  const float* Rim   = (const float*)d_in[3];
  const float* h0    = (const float*)d_in[4];
  float* out = (float*)d_out;

  modal_filter_kernel<<<DD, TPB, 0, stream>>>(r, theta, Rre, Rim, h0, out);
}